// Round 8
// baseline (233.640 us; speedup 1.0000x reference)
//
#include <hip/hip_runtime.h>

#define B_   8
#define N_   2048
#define FIN  256
#define FOUT 64
#define ALPHA 0.2f

typedef __attribute__((ext_vector_type(8))) short bf16x8;
typedef __attribute__((ext_vector_type(8))) unsigned short u16x8;
typedef __attribute__((ext_vector_type(4))) float f32x4;

__device__ __forceinline__ float b2f(unsigned short u) {
    union { unsigned int u; float f; } v; v.u = ((unsigned int)u) << 16; return v.f;
}
// round-to-nearest-even f32 -> bf16
__device__ __forceinline__ unsigned short f2b(float f) {
    union { float f; unsigned int u; } v; v.f = f;
    unsigned int r = v.u + 0x7FFFu + ((v.u >> 16) & 1u);
    return (unsigned short)(r >> 16);
}

// ---- Kernel 1 (fused): h-GEMM + transpose + src/dst projections ----
// grid 256 x 256 thr; block = 64 rows of flattened [16384,256] x.
// MFMA h = x@W + b; accs go through LDS tileT (validated k_tr layout) to
// produce f-major hT, plus src/dst dot products. No h round-trip to HBM.
__global__ __launch_bounds__(256) void k_hgemm_tr(
    const float* __restrict__ x, const float* __restrict__ W,
    const float* __restrict__ bW, const float* __restrict__ asrc,
    const float* __restrict__ adst,
    unsigned short* __restrict__ hT, float* __restrict__ src, float* __restrict__ dst)
{
    __shared__ unsigned short tileT[FOUT * 72];   // [f][row], pitch 72
    __shared__ float as_s[FOUT], ad_s[FOUT];

    const int tid = threadIdx.x;
    const int wv = tid >> 6, lane = tid & 63;
    const int quad = lane >> 4, col = lane & 15;
    const int f = wv * 16 + col;

    if (tid < FOUT) { as_s[tid] = asrc[tid]; ad_s[tid] = adst[tid]; }

    bf16x8 Bf[8];
    #pragma unroll
    for (int kk = 0; kk < 8; ++kk) {
        bf16x8 t;
        #pragma unroll
        for (int j = 0; j < 8; ++j)
            t[j] = (short)f2b(W[(kk * 32 + quad * 8 + j) * FOUT + f]);
        Bf[kk] = t;
    }
    const float bias = bW[f];
    const int r0 = blockIdx.x * 64;
    const int b = r0 >> 11;
    const int j0b = r0 & (N_ - 1);

    #pragma unroll
    for (int rt = 0; rt < 4; ++rt) {
        const int rr = r0 + rt * 16;
        f32x4 acc = {0.f, 0.f, 0.f, 0.f};
        #pragma unroll
        for (int kk = 0; kk < 8; ++kk) {
            const float* xp = x + (size_t)(rr + col) * FIN + kk * 32 + quad * 8;
            float4 x0 = *(const float4*)xp;
            float4 x1 = *(const float4*)(xp + 4);
            bf16x8 Af;
            Af[0] = (short)f2b(x0.x); Af[1] = (short)f2b(x0.y);
            Af[2] = (short)f2b(x0.z); Af[3] = (short)f2b(x0.w);
            Af[4] = (short)f2b(x1.x); Af[5] = (short)f2b(x1.y);
            Af[6] = (short)f2b(x1.z); Af[7] = (short)f2b(x1.w);
            acc = __builtin_amdgcn_mfma_f32_16x16x32_bf16(Af, Bf[kk], acc, 0, 0, 0);
        }
        #pragma unroll
        for (int reg = 0; reg < 4; ++reg) {
            int row = rt * 16 + quad * 4 + reg;       // block-local row
            tileT[f * 72 + row] = f2b(acc[reg] + bias);
        }
    }
    __syncthreads();

    {   // src/dst dots: thread = row i (0..63) x f-group (0..3) of 16
        const int i = tid >> 2, fb = (tid & 3) * 16;
        float sp = 0.f, dp = 0.f;
        #pragma unroll
        for (int k = 0; k < 16; ++k) {
            float hv = b2f(tileT[(fb + k) * 72 + i]);
            sp += hv * as_s[fb + k]; dp += hv * ad_s[fb + k];
        }
        sp += __shfl_xor(sp, 1); sp += __shfl_xor(sp, 2);
        dp += __shfl_xor(dp, 1); dp += __shfl_xor(dp, 2);
        if ((tid & 3) == 0) { src[r0 + i] = sp; dst[r0 + i] = dp; }
    }
    {   // hT writeout: thread = f (0..63) x row-quarter, vector b128 reads
        const int fq = tid >> 2, ic = (tid & 3) * 16;
        u16x8 o0 = *(const u16x8*)&tileT[fq * 72 + ic];
        u16x8 o1 = *(const u16x8*)&tileT[fq * 72 + ic + 8];
        unsigned short* op = hT + (size_t)(b * FOUT + fq) * N_ + j0b + ic;
        *(u16x8*)op = o0;
        *(u16x8*)(op + 8) = o1;
    }
}

// ---- Kernel 2: fused attention; 16-row i-tiles for 3 blocks/CU occupancy ----
// 1024 blocks = 8 batches x 128 i-tiles (16 rows); 256 thr = 4 waves.
// dbuf LDS, one barrier/tile, depth-1 register prefetch (R7 showed depth-2 neutral).
__global__ __launch_bounds__(256) void k_attn(
    const int* __restrict__ adj, const float* __restrict__ src, const float* __restrict__ dst,
    const unsigned short* __restrict__ hT, const float* __restrict__ abp,
    float* __restrict__ out)
{
    __shared__ unsigned short h_s[2][64 * 136];  // [f][j-local]
    __shared__ unsigned short w_s[2][16 * 136];  // [i-local][j-local]
    __shared__ float src_s[16];
    __shared__ float l_s[16];

    const int tid = threadIdx.x;
    const int wv = tid >> 6, lane = tid & 63;
    const int quad = lane >> 4, col = lane & 15;
    const int b = blockIdx.x >> 7;
    const int i0 = (blockIdx.x & 127) * 16;

    if (tid < 16) src_s[tid] = src[b * N_ + i0 + tid];
    __syncthreads();

    const int il = tid >> 4, jg = tid & 15;         // w-phase: row 0..15, j-group 0..15 (8 j each)
    const float srci = src_s[il] + abp[0];
    const int fq = tid >> 2, q4 = tid & 3;          // hT staging: feat 0..63, j-quarter
    const unsigned short* hTbase = hT + (size_t)(b * FOUT + fq) * N_ + q4 * 32;
    const int* adjbase = adj + (size_t)(b * N_ + i0 + il) * N_ + jg * 8;
    const float* dstbase = dst + b * N_ + jg * 8;

    // prefetch tile 0
    u16x8 hv0 = *(const u16x8*)(hTbase);
    u16x8 hv1 = *(const u16x8*)(hTbase + 8);
    u16x8 hv2 = *(const u16x8*)(hTbase + 16);
    u16x8 hv3 = *(const u16x8*)(hTbase + 24);
    int4 a0 = *(const int4*)(adjbase);
    int4 a1 = *(const int4*)(adjbase + 4);
    float4 d0 = *(const float4*)(dstbase);
    float4 d1 = *(const float4*)(dstbase + 4);

    float lsum = 0.f;
    f32x4 acc0 = {0, 0, 0, 0};

    for (int jt = 0; jt < 16; ++jt) {
        const int buf = jt & 1;
        {   // stage hT regs -> LDS
            unsigned short* q = &h_s[buf][fq * 136 + q4 * 32];
            *(u16x8*)q = hv0; *(u16x8*)(q + 8) = hv1;
            *(u16x8*)(q + 16) = hv2; *(u16x8*)(q + 24) = hv3;
        }
        {   // w tile [16 i][128 j]: 8 j per thread
            int av[8] = {a0.x, a0.y, a0.z, a0.w, a1.x, a1.y, a1.z, a1.w};
            float dv[8] = {d0.x, d0.y, d0.z, d0.w, d1.x, d1.y, d1.z, d1.w};
            u16x8 p0;
            float ls = 0.f;
            #pragma unroll
            for (int k = 0; k < 8; ++k) {
                float e = srci + dv[k];
                e = e > 0.f ? e : ALPHA * e;
                float wval = av[k] > 0 ? __expf(e) : 0.f;
                unsigned short wb = f2b(wval);
                ls += b2f(wb);   // denominator from SAME rounded weights as numerator
                p0[k] = wb;
            }
            lsum += ls;
            *(u16x8*)&w_s[buf][il * 136 + jg * 8] = p0;
        }
        __syncthreads();
        {   // prefetch next tile (depth 1)
            const int jn = ((jt + 1) & 15) * 128;
            hv0 = *(const u16x8*)(hTbase + jn);
            hv1 = *(const u16x8*)(hTbase + jn + 8);
            hv2 = *(const u16x8*)(hTbase + jn + 16);
            hv3 = *(const u16x8*)(hTbase + jn + 24);
            a0 = *(const int4*)(adjbase + jn);
            a1 = *(const int4*)(adjbase + jn + 4);
            d0 = *(const float4*)(dstbase + jn);
            d1 = *(const float4*)(dstbase + jn + 4);
        }
        {   // PV: acc[16x64] += w[16x128] @ h[128x64]
            #pragma unroll
            for (int kk = 0; kk < 4; ++kk) {
                bf16x8 A0 = *(const bf16x8*)&w_s[buf][col * 136 + kk * 32 + quad * 8];
                bf16x8 Bf = *(const bf16x8*)&h_s[buf][(wv * 16 + col) * 136 + kk * 32 + quad * 8];
                acc0 = __builtin_amdgcn_mfma_f32_16x16x32_bf16(A0, Bf, acc0, 0, 0, 0);
            }
        }
        // next iteration writes the OTHER buffer — no second barrier
    }

    lsum += __shfl_xor(lsum, 1);
    lsum += __shfl_xor(lsum, 2);
    lsum += __shfl_xor(lsum, 4);
    lsum += __shfl_xor(lsum, 8);
    if (jg == 0) l_s[il] = lsum;
    __syncthreads();

    #pragma unroll
    for (int reg = 0; reg < 4; ++reg) {
        int row = quad * 4 + reg;
        float l = l_s[row];
        l = l > 0.f ? l : 1.f;
        float v = acc0[reg] / l;
        v = v > 0.f ? v : (__expf(v) - 1.f);   // ELU(alpha=1)
        out[(size_t)(b * N_ + i0 + row) * FOUT + wv * 16 + col] = v;
    }
}

extern "C" void kernel_launch(void* const* d_in, const int* in_sizes, int n_in,
                              void* d_out, int out_size, void* d_ws, size_t ws_size,
                              hipStream_t stream)
{
    const float* x    = (const float*)d_in[0];
    const int*   adj  = (const int*)d_in[1];
    const float* W    = (const float*)d_in[2];
    const float* bW   = (const float*)d_in[3];
    const float* asrc = (const float*)d_in[4];
    const float* adst = (const float*)d_in[5];
    const float* abp  = (const float*)d_in[6];
    float* out = (float*)d_out;

    char* ws = (char*)d_ws;
    unsigned short* hT = (unsigned short*)ws;                               // 2 MB
    float* src = (float*)(ws + (size_t)2 * 1024 * 1024);                    // 64 KB
    float* dst = (float*)(ws + (size_t)2 * 1024 * 1024 + 64 * 1024);        // 64 KB

    k_hgemm_tr<<<256, 256, 0, stream>>>(x, W, bW, asrc, adst, hT, src, dst);
    k_attn<<<1024, 256, 0, stream>>>(adj, src, dst, hT, abp, out);
}

// Round 9
// 221.875 us; speedup vs baseline: 1.0530x; 1.0530x over previous
//
#include <hip/hip_runtime.h>

#define B_   8
#define N_   2048
#define FIN  256
#define FOUT 64
#define ALPHA 0.2f

typedef __attribute__((ext_vector_type(8))) short bf16x8;
typedef __attribute__((ext_vector_type(8))) unsigned short u16x8;
typedef __attribute__((ext_vector_type(4))) float f32x4;

__device__ __forceinline__ float b2f(unsigned short u) {
    union { unsigned int u; float f; } v; v.u = ((unsigned int)u) << 16; return v.f;
}
// round-to-nearest-even f32 -> bf16
__device__ __forceinline__ unsigned short f2b(float f) {
    union { float f; unsigned int u; } v; v.f = f;
    unsigned int r = v.u + 0x7FFFu + ((v.u >> 16) & 1u);
    return (unsigned short)(r >> 16);
}

// ---- Kernel 1 (fused): h-GEMM + transpose + src/dst projections ----
// grid 256 x 256 thr; block = 64 rows of flattened [16384,256] x.
__global__ __launch_bounds__(256) void k_hgemm_tr(
    const float* __restrict__ x, const float* __restrict__ W,
    const float* __restrict__ bW, const float* __restrict__ asrc,
    const float* __restrict__ adst,
    unsigned short* __restrict__ hT, float* __restrict__ src, float* __restrict__ dst)
{
    __shared__ unsigned short tileT[FOUT * 72];   // [f][row], pitch 72
    __shared__ float as_s[FOUT], ad_s[FOUT];

    const int tid = threadIdx.x;
    const int wv = tid >> 6, lane = tid & 63;
    const int quad = lane >> 4, col = lane & 15;
    const int f = wv * 16 + col;

    if (tid < FOUT) { as_s[tid] = asrc[tid]; ad_s[tid] = adst[tid]; }

    bf16x8 Bf[8];
    #pragma unroll
    for (int kk = 0; kk < 8; ++kk) {
        bf16x8 t;
        #pragma unroll
        for (int j = 0; j < 8; ++j)
            t[j] = (short)f2b(W[(kk * 32 + quad * 8 + j) * FOUT + f]);
        Bf[kk] = t;
    }
    const float bias = bW[f];
    const int r0 = blockIdx.x * 64;
    const int b = r0 >> 11;
    const int j0b = r0 & (N_ - 1);

    #pragma unroll
    for (int rt = 0; rt < 4; ++rt) {
        const int rr = r0 + rt * 16;
        f32x4 acc = {0.f, 0.f, 0.f, 0.f};
        #pragma unroll
        for (int kk = 0; kk < 8; ++kk) {
            const float* xp = x + (size_t)(rr + col) * FIN + kk * 32 + quad * 8;
            float4 x0 = *(const float4*)xp;
            float4 x1 = *(const float4*)(xp + 4);
            bf16x8 Af;
            Af[0] = (short)f2b(x0.x); Af[1] = (short)f2b(x0.y);
            Af[2] = (short)f2b(x0.z); Af[3] = (short)f2b(x0.w);
            Af[4] = (short)f2b(x1.x); Af[5] = (short)f2b(x1.y);
            Af[6] = (short)f2b(x1.z); Af[7] = (short)f2b(x1.w);
            acc = __builtin_amdgcn_mfma_f32_16x16x32_bf16(Af, Bf[kk], acc, 0, 0, 0);
        }
        #pragma unroll
        for (int reg = 0; reg < 4; ++reg) {
            int row = rt * 16 + quad * 4 + reg;       // block-local row
            tileT[f * 72 + row] = f2b(acc[reg] + bias);
        }
    }
    __syncthreads();

    {   // src/dst dots: thread = row i (0..63) x f-group (0..3) of 16
        const int i = tid >> 2, fb = (tid & 3) * 16;
        float sp = 0.f, dp = 0.f;
        #pragma unroll
        for (int k = 0; k < 16; ++k) {
            float hv = b2f(tileT[(fb + k) * 72 + i]);
            sp += hv * as_s[fb + k]; dp += hv * ad_s[fb + k];
        }
        sp += __shfl_xor(sp, 1); sp += __shfl_xor(sp, 2);
        dp += __shfl_xor(dp, 1); dp += __shfl_xor(dp, 2);
        if ((tid & 3) == 0) { src[r0 + i] = sp; dst[r0 + i] = dp; }
    }
    {   // hT writeout: thread = f (0..63) x row-quarter, vector b128 reads
        const int fq = tid >> 2, ic = (tid & 3) * 16;
        u16x8 o0 = *(const u16x8*)&tileT[fq * 72 + ic];
        u16x8 o1 = *(const u16x8*)&tileT[fq * 72 + ic + 8];
        unsigned short* op = hT + (size_t)(b * FOUT + fq) * N_ + j0b + ic;
        *(u16x8*)op = o0;
        *(u16x8*)(op + 8) = o1;
    }
}

// ---- Kernel 2: fused attention (R6-proven 32-row tiles, dbuf, depth-1) ----
// 512 blocks = 8 batches x 64 i-tiles (32 rows); 256 thr = 4 waves.
__global__ __launch_bounds__(256) void k_attn(
    const int* __restrict__ adj, const float* __restrict__ src, const float* __restrict__ dst,
    const unsigned short* __restrict__ hT, const float* __restrict__ abp,
    float* __restrict__ out)
{
    __shared__ unsigned short h_s[2][64 * 136];
    __shared__ unsigned short w_s[2][32 * 136];
    __shared__ float src_s[32];
    __shared__ float l_s[32];

    const int tid = threadIdx.x;
    const int wv = tid >> 6, lane = tid & 63;
    const int quad = lane >> 4, col = lane & 15;
    const int b = blockIdx.x >> 6;
    const int i0 = (blockIdx.x & 63) * 32;

    if (tid < 32) src_s[tid] = src[b * N_ + i0 + tid];
    __syncthreads();

    const int il = tid >> 3, jg = tid & 7;          // w-phase: row 0..31, j-group 0..7
    const float srci = src_s[il] + abp[0];
    const int fq = tid >> 2, q4 = tid & 3;          // hT staging: feat 0..63, j-quarter
    const unsigned short* hTbase = hT + (size_t)(b * FOUT + fq) * N_ + q4 * 32;
    const int* adjbase = adj + (size_t)(b * N_ + i0 + il) * N_ + jg * 16;
    const float* dstbase = dst + b * N_ + jg * 16;

    // prefetch tile 0 into registers
    u16x8 hv0 = *(const u16x8*)(hTbase);
    u16x8 hv1 = *(const u16x8*)(hTbase + 8);
    u16x8 hv2 = *(const u16x8*)(hTbase + 16);
    u16x8 hv3 = *(const u16x8*)(hTbase + 24);
    int4 a0 = *(const int4*)(adjbase);
    int4 a1 = *(const int4*)(adjbase + 4);
    int4 a2 = *(const int4*)(adjbase + 8);
    int4 a3 = *(const int4*)(adjbase + 12);
    float4 d0 = *(const float4*)(dstbase);
    float4 d1 = *(const float4*)(dstbase + 4);
    float4 d2 = *(const float4*)(dstbase + 8);
    float4 d3 = *(const float4*)(dstbase + 12);

    float lsum = 0.f;
    f32x4 acc0 = {0, 0, 0, 0}, acc1 = {0, 0, 0, 0};

    for (int jt = 0; jt < 16; ++jt) {
        const int buf = jt & 1;
        {   // stage hT regs -> LDS
            unsigned short* q = &h_s[buf][fq * 136 + q4 * 32];
            *(u16x8*)q = hv0; *(u16x8*)(q + 8) = hv1;
            *(u16x8*)(q + 16) = hv2; *(u16x8*)(q + 24) = hv3;
        }
        {   // w tile [32 i][128 j] from regs
            int av[16] = {a0.x, a0.y, a0.z, a0.w, a1.x, a1.y, a1.z, a1.w,
                          a2.x, a2.y, a2.z, a2.w, a3.x, a3.y, a3.z, a3.w};
            float dv[16] = {d0.x, d0.y, d0.z, d0.w, d1.x, d1.y, d1.z, d1.w,
                            d2.x, d2.y, d2.z, d2.w, d3.x, d3.y, d3.z, d3.w};
            u16x8 p0, p1;
            float ls = 0.f;
            #pragma unroll
            for (int k = 0; k < 16; ++k) {
                float e = srci + dv[k];
                e = e > 0.f ? e : ALPHA * e;
                float wval = av[k] > 0 ? __expf(e) : 0.f;
                unsigned short wb = f2b(wval);
                ls += b2f(wb);   // denominator from SAME rounded weights as numerator
                if (k < 8) p0[k] = wb; else p1[k - 8] = wb;
            }
            lsum += ls;
            unsigned short* q = &w_s[buf][il * 136 + jg * 16];
            *(u16x8*)q = p0; *(u16x8*)(q + 8) = p1;
        }
        __syncthreads();
        {   // prefetch next tile (depth 1; jt=15 wraps harmlessly)
            const int jn = ((jt + 1) & 15) * 128;
            hv0 = *(const u16x8*)(hTbase + jn);
            hv1 = *(const u16x8*)(hTbase + jn + 8);
            hv2 = *(const u16x8*)(hTbase + jn + 16);
            hv3 = *(const u16x8*)(hTbase + jn + 24);
            a0 = *(const int4*)(adjbase + jn);
            a1 = *(const int4*)(adjbase + jn + 4);
            a2 = *(const int4*)(adjbase + jn + 8);
            a3 = *(const int4*)(adjbase + jn + 12);
            d0 = *(const float4*)(dstbase + jn);
            d1 = *(const float4*)(dstbase + jn + 4);
            d2 = *(const float4*)(dstbase + jn + 8);
            d3 = *(const float4*)(dstbase + jn + 12);
        }
        {   // PV: acc[32x64] += w[32x128] @ h[128x64]
            #pragma unroll
            for (int kk = 0; kk < 4; ++kk) {
                bf16x8 A0 = *(const bf16x8*)&w_s[buf][col * 136 + kk * 32 + quad * 8];
                bf16x8 A1 = *(const bf16x8*)&w_s[buf][(16 + col) * 136 + kk * 32 + quad * 8];
                bf16x8 Bf = *(const bf16x8*)&h_s[buf][(wv * 16 + col) * 136 + kk * 32 + quad * 8];
                acc0 = __builtin_amdgcn_mfma_f32_16x16x32_bf16(A0, Bf, acc0, 0, 0, 0);
                acc1 = __builtin_amdgcn_mfma_f32_16x16x32_bf16(A1, Bf, acc1, 0, 0, 0);
            }
        }
        // next iteration writes the OTHER buffer — no second barrier
    }

    lsum += __shfl_xor(lsum, 1);
    lsum += __shfl_xor(lsum, 2);
    lsum += __shfl_xor(lsum, 4);
    if (jg == 0) l_s[il] = lsum;
    __syncthreads();

    #pragma unroll
    for (int m = 0; m < 2; ++m) {
        f32x4 a = m ? acc1 : acc0;
        #pragma unroll
        for (int reg = 0; reg < 4; ++reg) {
            int row = m * 16 + quad * 4 + reg;
            float l = l_s[row];
            l = l > 0.f ? l : 1.f;
            float v = a[reg] / l;
            v = v > 0.f ? v : (__expf(v) - 1.f);   // ELU(alpha=1)
            out[(size_t)(b * N_ + i0 + row) * FOUT + wv * 16 + col] = v;
        }
    }
}

extern "C" void kernel_launch(void* const* d_in, const int* in_sizes, int n_in,
                              void* d_out, int out_size, void* d_ws, size_t ws_size,
                              hipStream_t stream)
{
    const float* x    = (const float*)d_in[0];
    const int*   adj  = (const int*)d_in[1];
    const float* W    = (const float*)d_in[2];
    const float* bW   = (const float*)d_in[3];
    const float* asrc = (const float*)d_in[4];
    const float* adst = (const float*)d_in[5];
    const float* abp  = (const float*)d_in[6];
    float* out = (float*)d_out;

    char* ws = (char*)d_ws;
    unsigned short* hT = (unsigned short*)ws;                               // 2 MB
    float* src = (float*)(ws + (size_t)2 * 1024 * 1024);                    // 64 KB
    float* dst = (float*)(ws + (size_t)2 * 1024 * 1024 + 64 * 1024);        // 64 KB

    k_hgemm_tr<<<256, 256, 0, stream>>>(x, W, bW, asrc, adst, hT, src, dst);
    k_attn<<<512, 256, 0, stream>>>(adj, src, dst, hT, abp, out);
}